// Round 1
// baseline (4676.847 us; speedup 1.0000x reference)
//
#include <hip/hip_runtime.h>

// GRU scan: T=512, B=64, D=H=512.  out[t] = h_{t+1}, fp32 [T,B,H].
//
// Structure:
//  K1 prep:   cast x->bf16, transpose+cast Wi,Wh -> [3H][K] bf16, init h state, zero barrier
//  K2 gi_gemm: Gi[T*B,3H] = Xb @ Wi + bi  (bf16 MFMA, 128x128 tiles), stored bf16
//  K3 recurrent: persistent, 32 WGs x 256 thr. WG g owns 16 hidden units (48 gate cols).
//     Wh fragments live in REGISTERS (192 VGPRs/lane) for all 512 steps.
//     h state double-buffered bf16 in ws; grid barrier (monotonic counter) per step.

#define T_STEPS 512
#define NWG 32

typedef __attribute__((ext_vector_type(8))) short bhalf8;
typedef __attribute__((ext_vector_type(4))) float floatx4;

__device__ inline float bf2f(unsigned short u) {
  union { unsigned u; float f; } v; v.u = ((unsigned)u) << 16; return v.f;
}
__device__ inline unsigned short f2bf(float f) {
  union { float f; unsigned u; } v; v.f = f;
  unsigned x = v.u;
  return (unsigned short)((x + 0x7fffu + ((x >> 16) & 1u)) >> 16);
}

// ---- workspace layout (bytes) ----
#define O_BAR 0                    //   512 B: arr @+0, gen @+128
#define O_HB  1024                 //  Hb[2][64][512] bf16 = 131072
#define O_WIT 132096               //  WiT [1536][512] bf16 = 1572864
#define O_WHT 1704960              //  WhT [1536][512] bf16 = 1572864
#define O_GI  3277824              //  Gi [32768][1536] bf16 = 100663296
#define O_XB  103941120ULL         //  Xb [32768][512] bf16 = 33554432
#define WS_NEED 137495552ULL       //  ~131.1 MiB

// ---------------- K1: prep ----------------
__global__ void prep_kernel(const float* __restrict__ x, const float* __restrict__ h0,
                            const float* __restrict__ Wi, const float* __restrict__ Wh,
                            char* __restrict__ ws) {
  unsigned short* Xb  = (unsigned short*)(ws + O_XB);
  unsigned short* WiT = (unsigned short*)(ws + O_WIT);
  unsigned short* WhT = (unsigned short*)(ws + O_WHT);
  unsigned short* Hb  = (unsigned short*)(ws + O_HB);
  int* bar = (int*)(ws + O_BAR);
  const long NX = 16777216, NW = 786432, NH = 32768;
  const long total = NX + 2 * NW + NH + 128;
  for (long i = (long)blockIdx.x * blockDim.x + threadIdx.x; i < total;
       i += (long)gridDim.x * blockDim.x) {
    if (i < NX) {
      Xb[i] = f2bf(x[i]);
    } else if (i < NX + NW) {
      long j = i - NX;                 // j = n*512 + k  (WiT[n][k] = Wi[k][n])
      long n = j >> 9, k = j & 511;
      WiT[j] = f2bf(Wi[k * 1536 + n]);
    } else if (i < NX + 2 * NW) {
      long j = i - NX - NW;
      long n = j >> 9, k = j & 511;
      WhT[j] = f2bf(Wh[k * 1536 + n]);
    } else if (i < NX + 2 * NW + NH) {
      long j = i - NX - 2 * NW;
      Hb[j] = f2bf(h0[j]);             // state buffer 0 only
    } else {
      bar[i - (NX + 2 * NW + NH)] = 0;
    }
  }
}

// ---------------- K2: Gi = Xb @ Wi + bi  (bf16 -> bf16) ----------------
// 128x128 tile, BK=32, 256 threads (4 waves, each a 64x64 quadrant of 4x4 MFMA tiles).
__global__ void gi_gemm(const unsigned short* __restrict__ Xb,
                        const unsigned short* __restrict__ WiT,
                        const float* __restrict__ bi,
                        unsigned short* __restrict__ Gi) {
  __shared__ unsigned short As[128 * 32];
  __shared__ unsigned short Bs[128 * 32];
  const int tid  = threadIdx.x;
  const int m0   = blockIdx.x * 128;
  const int n0   = blockIdx.y * 128;
  const int lane = tid & 63, wv = tid >> 6;
  const int quad = lane >> 4, l16 = lane & 15;
  const int wm = (wv & 1) * 64, wn = (wv >> 1) * 64;
  const int sr = tid >> 1, sc = (tid & 1) * 16;   // staging: row, col-offset (elements)

  floatx4 acc[4][4] = {};

  for (int kb = 0; kb < 16; ++kb) {
    const int k0 = kb * 32;
    __syncthreads();
    // stage A tile [128][32] and B tile [128][32] (both [row][k] bf16, contiguous k)
    *(bhalf8*)(&As[sr * 32 + sc])     = *(const bhalf8*)(&Xb[(long)(m0 + sr) * 512 + k0 + sc]);
    *(bhalf8*)(&As[sr * 32 + sc + 8]) = *(const bhalf8*)(&Xb[(long)(m0 + sr) * 512 + k0 + sc + 8]);
    *(bhalf8*)(&Bs[sr * 32 + sc])     = *(const bhalf8*)(&WiT[(long)(n0 + sr) * 512 + k0 + sc]);
    *(bhalf8*)(&Bs[sr * 32 + sc + 8]) = *(const bhalf8*)(&WiT[(long)(n0 + sr) * 512 + k0 + sc + 8]);
    __syncthreads();

    bhalf8 af[4], bf[4];
#pragma unroll
    for (int i = 0; i < 4; ++i)
      af[i] = *(const bhalf8*)(&As[(wm + i * 16 + l16) * 32 + quad * 8]);
#pragma unroll
    for (int j = 0; j < 4; ++j)
      bf[j] = *(const bhalf8*)(&Bs[(wn + j * 16 + l16) * 32 + quad * 8]);
#pragma unroll
    for (int i = 0; i < 4; ++i)
#pragma unroll
      for (int j = 0; j < 4; ++j)
        acc[i][j] = __builtin_amdgcn_mfma_f32_16x16x32_bf16(af[i], bf[j], acc[i][j], 0, 0, 0);
  }

#pragma unroll
  for (int i = 0; i < 4; ++i)
#pragma unroll
    for (int j = 0; j < 4; ++j) {
      const int col = n0 + wn + j * 16 + l16;
      const float bv = bi[col];
#pragma unroll
      for (int r = 0; r < 4; ++r) {
        const int row = m0 + wm + i * 16 + quad * 4 + r;
        Gi[(long)row * 1536 + col] = f2bf(acc[i][j][r] + bv);
      }
    }
}

// ---------------- K3: persistent recurrence ----------------
__launch_bounds__(256, 1)
__global__ void recurrent_kernel(const unsigned short* __restrict__ WhT,
                                 const unsigned short* __restrict__ Gi,
                                 const float* __restrict__ h0,
                                 const float* __restrict__ bhn,
                                 unsigned short* Hb,   // [2][64][512] bf16
                                 float* __restrict__ out,
                                 int* bar) {
  const int g    = blockIdx.x;        // hidden slice: units [16g, 16g+16)
  const int tid  = threadIdx.x;
  const int wv   = tid >> 6;          // M-tile (16 batch rows)
  const int lane = tid & 63;
  const int quad = lane >> 4, l16 = lane & 15;
  const int gcol = g * 16 + l16;      // this lane's hidden unit (C-layout col)

  // Wh fragments -> registers, persistent for all 512 steps.
  // Bf[gate][ks] lane element j = Wh[k = ks*32 + quad*8 + j][n = gate*512 + gcol]
  bhalf8 Bf[3][16];
#pragma unroll
  for (int gt = 0; gt < 3; ++gt) {
    const unsigned short* wp = WhT + (long)(gt * 512 + gcol) * 512;
#pragma unroll
    for (int ks = 0; ks < 16; ++ks)
      Bf[gt][ks] = *(const bhalf8*)(wp + ks * 32 + quad * 8);
  }
  const float bhn_v = bhn[gcol];

  // carried state (exact fp32) for this lane's 4 C-layout rows
  float hprev[4];
#pragma unroll
  for (int r = 0; r < 4; ++r)
    hprev[r] = h0[(wv * 16 + quad * 4 + r) * 512 + gcol];

  int* arr = bar;        // monotonic arrival counter
  int* gen = bar + 32;   // generation (separate cache line)

  for (int t = 0; t < T_STEPS; ++t) {
    const unsigned short* hin  = Hb + (t & 1) * (64 * 512);
    unsigned short*       hout = Hb + ((t + 1) & 1) * (64 * 512);

    floatx4 racc = {0.f, 0.f, 0.f, 0.f};
    floatx4 zacc = {0.f, 0.f, 0.f, 0.f};
    floatx4 nacc = {0.f, 0.f, 0.f, 0.f};
    const unsigned short* ap = hin + (wv * 16 + l16) * 512 + quad * 8;
#pragma unroll
    for (int ks = 0; ks < 16; ++ks) {
      bhalf8 af = *(const bhalf8*)(ap + ks * 32);
      racc = __builtin_amdgcn_mfma_f32_16x16x32_bf16(af, Bf[0][ks], racc, 0, 0, 0);
      zacc = __builtin_amdgcn_mfma_f32_16x16x32_bf16(af, Bf[1][ks], zacc, 0, 0, 0);
      nacc = __builtin_amdgcn_mfma_f32_16x16x32_bf16(af, Bf[2][ks], nacc, 0, 0, 0);
    }

    const long gibase = (long)t * 64 * 1536;
#pragma unroll
    for (int r = 0; r < 4; ++r) {
      const int brow = wv * 16 + quad * 4 + r;
      const long gb = gibase + (long)brow * 1536 + gcol;
      const float i_r = bf2f(Gi[gb]);
      const float i_z = bf2f(Gi[gb + 512]);
      const float i_n = bf2f(Gi[gb + 1024]);
      const float rg = 1.f / (1.f + __expf(-(i_r + racc[r])));
      const float zg = 1.f / (1.f + __expf(-(i_z + zacc[r])));
      const float pre = i_n + rg * (nacc[r] + bhn_v);
      const float e2 = __expf(2.f * pre);
      const float ng = 1.f - 2.f / (e2 + 1.f);      // tanh, saturates cleanly
      const float hn = (1.f - zg) * ng + zg * hprev[r];
      hprev[r] = hn;
      out[((long)t * 64 + brow) * 512 + gcol] = hn;
      hout[brow * 512 + gcol] = f2bf(hn);
    }

    // ---- grid barrier (monotonic, sense-free) ----
    __syncthreads();               // drains vmem (compiler emits vmcnt(0) before s_barrier)
    if (tid == 0) {
      __threadfence();             // release: make h writes agent-visible (wbL2)
      int prev = __hip_atomic_fetch_add(arr, 1, __ATOMIC_ACQ_REL, __HIP_MEMORY_SCOPE_AGENT);
      if (prev == NWG * (t + 1) - 1) {
        __hip_atomic_store(gen, t + 1, __ATOMIC_RELEASE, __HIP_MEMORY_SCOPE_AGENT);
      } else {
        while (__hip_atomic_load(gen, __ATOMIC_ACQUIRE, __HIP_MEMORY_SCOPE_AGENT) < t + 1)
          __builtin_amdgcn_s_sleep(1);
      }
      __threadfence();             // acquire: invalidate L1/L2 before reading fresh h
    }
    __syncthreads();
  }
}

extern "C" void kernel_launch(void* const* d_in, const int* in_sizes, int n_in,
                              void* d_out, int out_size, void* d_ws, size_t ws_size,
                              hipStream_t stream) {
  const float* x   = (const float*)d_in[0];
  const float* h0  = (const float*)d_in[1];
  const float* Wi  = (const float*)d_in[2];
  const float* Wh  = (const float*)d_in[3];
  const float* bi  = (const float*)d_in[4];
  const float* bhn = (const float*)d_in[5];
  float* out = (float*)d_out;
  char* ws = (char*)d_ws;
  if (ws_size < WS_NEED) return;  // insufficient workspace: fail visibly, don't corrupt

  prep_kernel<<<4096, 256, 0, stream>>>(x, h0, Wi, Wh, ws);
  gi_gemm<<<dim3(256, 12), 256, 0, stream>>>(
      (const unsigned short*)(ws + O_XB), (const unsigned short*)(ws + O_WIT),
      bi, (unsigned short*)(ws + O_GI));
  recurrent_kernel<<<NWG, 256, 0, stream>>>(
      (const unsigned short*)(ws + O_WHT), (const unsigned short*)(ws + O_GI),
      h0, bhn, (unsigned short*)(ws + O_HB), out, (int*)(ws + O_BAR));
}

// Round 2
// 3321.999 us; speedup vs baseline: 1.4078x; 1.4078x over previous
//
#include <hip/hip_runtime.h>

// GRU scan: T=512, B=64, D=H=512.  out[t] = h_{t+1}, fp32 [T,B,H].
//
//  K1 prep:   cast x->bf16, transpose+cast Wi,Wh -> [3H][K] bf16, init h state, zero flags
//  K2 gi_gemm: Gi[T*B,3H] = Xb @ Wi + bi  (bf16 MFMA, 128x128 tiles), stored bf16
//  K3 recurrent: persistent, 32 WGs x 256 thr. WG g owns 16 hidden units (48 gate cols).
//     Wh fragments in REGISTERS for all 512 steps. h exchanged via relaxed agent-scope
//     (sc0 sc1, L3-coherent, cache-bypassing) atomics; flag-array barrier, NO fences
//     (fences were emitting buffer_inv -> full L1/L2 invalidation per step in R1).

#define T_STEPS 512
#define NWG 32

typedef __attribute__((ext_vector_type(8))) short bhalf8;
typedef __attribute__((ext_vector_type(4))) float floatx4;

__device__ inline float bf2f(unsigned short u) {
  union { unsigned u; float f; } v; v.u = ((unsigned)u) << 16; return v.f;
}
__device__ inline unsigned short f2bf(float f) {
  union { float f; unsigned u; } v; v.f = f;
  unsigned x = v.u;
  return (unsigned short)((x + 0x7fffu + ((x >> 16) & 1u)) >> 16);
}

// ---- workspace layout (bytes) ----
#define O_BAR 0                    //   512 B: flags[32] @+0 (one 128B line)
#define O_HB  1024                 //  Hb[2][64][512] bf16 = 131072
#define O_WIT 132096               //  WiT [1536][512] bf16 = 1572864
#define O_WHT 1704960              //  WhT [1536][512] bf16 = 1572864
#define O_GI  3277824              //  Gi [32768][1536] bf16 = 100663296
#define O_XB  103941120ULL         //  Xb [32768][512] bf16 = 33554432
#define WS_NEED 137495552ULL       //  ~131.1 MiB

// ---------------- K1: prep ----------------
__global__ void prep_kernel(const float* __restrict__ x, const float* __restrict__ h0,
                            const float* __restrict__ Wi, const float* __restrict__ Wh,
                            char* __restrict__ ws) {
  unsigned short* Xb  = (unsigned short*)(ws + O_XB);
  unsigned short* WiT = (unsigned short*)(ws + O_WIT);
  unsigned short* WhT = (unsigned short*)(ws + O_WHT);
  unsigned short* Hb  = (unsigned short*)(ws + O_HB);
  int* bar = (int*)(ws + O_BAR);
  const long NX = 16777216, NW = 786432, NH = 32768;
  const long total = NX + 2 * NW + NH + 128;
  for (long i = (long)blockIdx.x * blockDim.x + threadIdx.x; i < total;
       i += (long)gridDim.x * blockDim.x) {
    if (i < NX) {
      Xb[i] = f2bf(x[i]);
    } else if (i < NX + NW) {
      long j = i - NX;                 // j = n*512 + k  (WiT[n][k] = Wi[k][n])
      long n = j >> 9, k = j & 511;
      WiT[j] = f2bf(Wi[k * 1536 + n]);
    } else if (i < NX + 2 * NW) {
      long j = i - NX - NW;
      long n = j >> 9, k = j & 511;
      WhT[j] = f2bf(Wh[k * 1536 + n]);
    } else if (i < NX + 2 * NW + NH) {
      long j = i - NX - 2 * NW;
      Hb[j] = f2bf(h0[j]);             // state buffer 0 only
    } else {
      bar[i - (NX + 2 * NW + NH)] = 0;
    }
  }
}

// ---------------- K2: Gi = Xb @ Wi + bi  (bf16 -> bf16) ----------------
__global__ void gi_gemm(const unsigned short* __restrict__ Xb,
                        const unsigned short* __restrict__ WiT,
                        const float* __restrict__ bi,
                        unsigned short* __restrict__ Gi) {
  __shared__ unsigned short As[128 * 32];
  __shared__ unsigned short Bs[128 * 32];
  const int tid  = threadIdx.x;
  const int m0   = blockIdx.x * 128;
  const int n0   = blockIdx.y * 128;
  const int lane = tid & 63, wv = tid >> 6;
  const int quad = lane >> 4, l16 = lane & 15;
  const int wm = (wv & 1) * 64, wn = (wv >> 1) * 64;
  const int sr = tid >> 1, sc = (tid & 1) * 16;

  floatx4 acc[4][4] = {};

  for (int kb = 0; kb < 16; ++kb) {
    const int k0 = kb * 32;
    __syncthreads();
    *(bhalf8*)(&As[sr * 32 + sc])     = *(const bhalf8*)(&Xb[(long)(m0 + sr) * 512 + k0 + sc]);
    *(bhalf8*)(&As[sr * 32 + sc + 8]) = *(const bhalf8*)(&Xb[(long)(m0 + sr) * 512 + k0 + sc + 8]);
    *(bhalf8*)(&Bs[sr * 32 + sc])     = *(const bhalf8*)(&WiT[(long)(n0 + sr) * 512 + k0 + sc]);
    *(bhalf8*)(&Bs[sr * 32 + sc + 8]) = *(const bhalf8*)(&WiT[(long)(n0 + sr) * 512 + k0 + sc + 8]);
    __syncthreads();

    bhalf8 af[4], bf[4];
#pragma unroll
    for (int i = 0; i < 4; ++i)
      af[i] = *(const bhalf8*)(&As[(wm + i * 16 + l16) * 32 + quad * 8]);
#pragma unroll
    for (int j = 0; j < 4; ++j)
      bf[j] = *(const bhalf8*)(&Bs[(wn + j * 16 + l16) * 32 + quad * 8]);
#pragma unroll
    for (int i = 0; i < 4; ++i)
#pragma unroll
      for (int j = 0; j < 4; ++j)
        acc[i][j] = __builtin_amdgcn_mfma_f32_16x16x32_bf16(af[i], bf[j], acc[i][j], 0, 0, 0);
  }

#pragma unroll
  for (int i = 0; i < 4; ++i)
#pragma unroll
    for (int j = 0; j < 4; ++j) {
      const int col = n0 + wn + j * 16 + l16;
      const float bv = bi[col];
#pragma unroll
      for (int r = 0; r < 4; ++r) {
        const int row = m0 + wm + i * 16 + quad * 4 + r;
        Gi[(long)row * 1536 + col] = f2bf(acc[i][j][r] + bv);
      }
    }
}

// ---------------- K3: persistent recurrence ----------------
__launch_bounds__(256, 1)
__global__ void recurrent_kernel(const unsigned short* __restrict__ WhT,
                                 const unsigned short* __restrict__ Gi,
                                 const float* __restrict__ h0,
                                 const float* __restrict__ bhn,
                                 unsigned short* Hb,   // [2][64][512] bf16
                                 float* __restrict__ out,
                                 int* flags) {
  const int g    = blockIdx.x;        // hidden slice: units [16g, 16g+16)
  const int tid  = threadIdx.x;
  const int wv   = tid >> 6;          // M-tile (16 batch rows)
  const int lane = tid & 63;
  const int quad = lane >> 4, l16 = lane & 15;
  const int gcol = g * 16 + l16;      // this lane's hidden unit (C-layout col)

  // Wh fragments -> registers, persistent for all 512 steps.
  bhalf8 Bf[3][16];
#pragma unroll
  for (int gt = 0; gt < 3; ++gt) {
    const unsigned short* wp = WhT + (long)(gt * 512 + gcol) * 512;
#pragma unroll
    for (int ks = 0; ks < 16; ++ks)
      Bf[gt][ks] = *(const bhalf8*)(wp + ks * 32 + quad * 8);
  }
  const float bhn_v = bhn[gcol];

  float hprev[4];
#pragma unroll
  for (int r = 0; r < 4; ++r)
    hprev[r] = h0[(wv * 16 + quad * 4 + r) * 512 + gcol];

  // Gi prefetch for step 0
  float gi_r[4], gi_z[4], gi_n[4];
#pragma unroll
  for (int r = 0; r < 4; ++r) {
    const int brow = wv * 16 + quad * 4 + r;
    const long gb = (long)brow * 1536 + gcol;
    gi_r[r] = bf2f(Gi[gb]);
    gi_z[r] = bf2f(Gi[gb + 512]);
    gi_n[r] = bf2f(Gi[gb + 1024]);
  }

  for (int t = 0; t < T_STEPS; ++t) {
    const unsigned short* hin  = Hb + (t & 1) * (64 * 512);
    unsigned short*       hout = Hb + ((t + 1) & 1) * (64 * 512);

    // ---- load all h A-frags via L3-coherent bypass loads (issued back-to-back) ----
    const unsigned long long* ap =
        (const unsigned long long*)(hin + (wv * 16 + l16) * 512 + quad * 8);
    unsigned long long aq0[16], aq1[16];
#pragma unroll
    for (int ks = 0; ks < 16; ++ks) {
      aq0[ks] = __hip_atomic_load(ap + ks * 8,     __ATOMIC_RELAXED, __HIP_MEMORY_SCOPE_AGENT);
      aq1[ks] = __hip_atomic_load(ap + ks * 8 + 1, __ATOMIC_RELAXED, __HIP_MEMORY_SCOPE_AGENT);
    }

    floatx4 racc = {0.f, 0.f, 0.f, 0.f};
    floatx4 zacc = {0.f, 0.f, 0.f, 0.f};
    floatx4 nacc = {0.f, 0.f, 0.f, 0.f};
#pragma unroll
    for (int ks = 0; ks < 16; ++ks) {
      union { unsigned long long q[2]; bhalf8 v; } u;
      u.q[0] = aq0[ks]; u.q[1] = aq1[ks];
      racc = __builtin_amdgcn_mfma_f32_16x16x32_bf16(u.v, Bf[0][ks], racc, 0, 0, 0);
      zacc = __builtin_amdgcn_mfma_f32_16x16x32_bf16(u.v, Bf[1][ks], zacc, 0, 0, 0);
      nacc = __builtin_amdgcn_mfma_f32_16x16x32_bf16(u.v, Bf[2][ks], nacc, 0, 0, 0);
    }

    // ---- gates + h write (packed 2xbf16 bypass stores) ----
#pragma unroll
    for (int r = 0; r < 4; ++r) {
      const int brow = wv * 16 + quad * 4 + r;
      const float rg = 1.f / (1.f + __expf(-(gi_r[r] + racc[r])));
      const float zg = 1.f / (1.f + __expf(-(gi_z[r] + zacc[r])));
      const float pre = gi_n[r] + rg * (nacc[r] + bhn_v);
      const float e2 = __expf(2.f * pre);
      const float ng = 1.f - 2.f / (e2 + 1.f);      // tanh
      const float hn = (1.f - zg) * ng + zg * hprev[r];
      hprev[r] = hn;
      out[((long)t * 64 + brow) * 512 + gcol] = hn;
      const unsigned hb = (unsigned)f2bf(hn);
      const unsigned ob = __shfl_xor(hb, 1, 64);    // partner col (l16^1)
      if (!(l16 & 1)) {
        const unsigned packed = hb | (ob << 16);    // low col in low half
        __hip_atomic_store((unsigned*)(hout + brow * 512 + gcol), packed,
                           __ATOMIC_RELAXED, __HIP_MEMORY_SCOPE_AGENT);
      }
    }

    // ---- prefetch next step's Gi (immutable; overlaps barrier) ----
    if (t + 1 < T_STEPS) {
      const long gibase = (long)(t + 1) * 64 * 1536;
#pragma unroll
      for (int r = 0; r < 4; ++r) {
        const int brow = wv * 16 + quad * 4 + r;
        const long gb = gibase + (long)brow * 1536 + gcol;
        gi_r[r] = bf2f(Gi[gb]);
        gi_z[r] = bf2f(Gi[gb + 512]);
        gi_n[r] = bf2f(Gi[gb + 1024]);
      }
    }

    // ---- flag-array barrier: no RMW, no fences, no cache invalidation ----
    __syncthreads();   // all h stores drained (vmcnt(0) before s_barrier)
    if (tid == 0)
      __hip_atomic_store(&flags[g], t + 1, __ATOMIC_RELAXED, __HIP_MEMORY_SCOPE_AGENT);
    {
      const int want = t + 1;
      int v;
      do {
        v = __hip_atomic_load(&flags[lane & 31], __ATOMIC_RELAXED, __HIP_MEMORY_SCOPE_AGENT);
      } while (!__all(v >= want));
      __atomic_signal_fence(__ATOMIC_SEQ_CST);  // compiler-only acquire; h loads stay after poll
    }
  }
}

extern "C" void kernel_launch(void* const* d_in, const int* in_sizes, int n_in,
                              void* d_out, int out_size, void* d_ws, size_t ws_size,
                              hipStream_t stream) {
  const float* x   = (const float*)d_in[0];
  const float* h0  = (const float*)d_in[1];
  const float* Wi  = (const float*)d_in[2];
  const float* Wh  = (const float*)d_in[3];
  const float* bi  = (const float*)d_in[4];
  const float* bhn = (const float*)d_in[5];
  float* out = (float*)d_out;
  char* ws = (char*)d_ws;
  if (ws_size < WS_NEED) return;

  prep_kernel<<<4096, 256, 0, stream>>>(x, h0, Wi, Wh, ws);
  gi_gemm<<<dim3(256, 12), 256, 0, stream>>>(
      (const unsigned short*)(ws + O_XB), (const unsigned short*)(ws + O_WIT),
      bi, (unsigned short*)(ws + O_GI));
  recurrent_kernel<<<NWG, 256, 0, stream>>>(
      (const unsigned short*)(ws + O_WHT), (const unsigned short*)(ws + O_GI),
      h0, bhn, (unsigned short*)(ws + O_HB), out, (int*)(ws + O_BAR));
}

// Round 4
// 2414.332 us; speedup vs baseline: 1.9371x; 1.3759x over previous
//
#include <hip/hip_runtime.h>

// GRU scan: T=512, B=64, D=H=512.  out[t] = h_{t+1}, fp32 [T,B,H].
//
//  K1 prep:   cast x->bf16, transpose+cast Wi,Wh -> [3H][K] bf16, init Hseq[0], zero bar
//  K2 gi_gemm: Gi[T*B,3H] = Xb @ Wi + bi  (bf16 MFMA, 128x128 tiles), stored bf16
//  K3 recurrent: launch 256 WGs; elect 32 workers on ONE XCD (HW_REG_XCC_ID ticket).
//     Workers PROBE the same-L2 path (bounded CAS barrier); on success, per-step sync
//     runs entirely in the shared XCD L2 (atomic RMW/CAS execute in L2; h exchanged
//     via plain write-through stores + L1-cold reads of per-step buffers Hseq[t]).
//     On probe timeout (placement assumption wrong) -> agent-scope fallback (R2 path,
//     proven correct at ~6us/step). No inline asm anywhere.

#define T_STEPS 512
#define NWORK 32
#define NB_LAUNCH 256

typedef __attribute__((ext_vector_type(8))) short bhalf8;
typedef __attribute__((ext_vector_type(4))) float floatx4;

__device__ inline float bf2f(unsigned short u) {
  union { unsigned u; float f; } v; v.u = ((unsigned)u) << 16; return v.f;
}
__device__ inline unsigned short f2bf(float f) {
  union { float f; unsigned u; } v; v.f = f;
  unsigned x = v.u;
  return (unsigned short)((x + 0x7fffu + ((x >> 16) & 1u)) >> 16);
}

// ---- workspace layout (bytes) ----
// bar ints: cnt[512]@0, flags[32]@512, tick[8]@544, arrived@552, tick2@553,
//           pcnt@554, abortf@555, arrive2@556   (prep zeroes all 1024)
#define O_BAR 0                    //  4096 B
#define O_HB  4096                 //  Hseq[0] = h0 cast: [64][512] bf16 = 65536
#define O_WIT 69632                //  WiT [1536][512] bf16 = 1572864
#define O_WHT 1642496              //  WhT [1536][512] bf16 = 1572864
#define O_GI  3215360              //  Gi [32768][1536] bf16 = 100663296
#define O_XB  103878656ULL         //  Xb [32768][512] bf16 = 33554432 ; after K2 dies,
                                   //  reused as Hseq[1..512] (512 x 65536 B)
#define WS_NEED 137433088ULL       //  ~131.1 MiB (<= R1/R2's verified budget)

__device__ inline unsigned short* HS(char* ws, int t) {   // h buffer for step t
  return (t == 0) ? (unsigned short*)(ws + O_HB)
                  : (unsigned short*)(ws + O_XB + (long)(t - 1) * 65536);
}

// ---------------- K1: prep ----------------
__global__ void prep_kernel(const float* __restrict__ x, const float* __restrict__ h0,
                            const float* __restrict__ Wi, const float* __restrict__ Wh,
                            char* __restrict__ ws) {
  unsigned short* Xb  = (unsigned short*)(ws + O_XB);
  unsigned short* WiT = (unsigned short*)(ws + O_WIT);
  unsigned short* WhT = (unsigned short*)(ws + O_WHT);
  unsigned short* Hb0 = (unsigned short*)(ws + O_HB);
  int* bar = (int*)(ws + O_BAR);
  const long NX = 16777216, NW = 786432, NH = 32768;
  const long total = NX + 2 * NW + NH + 1024;
  for (long i = (long)blockIdx.x * blockDim.x + threadIdx.x; i < total;
       i += (long)gridDim.x * blockDim.x) {
    if (i < NX) {
      Xb[i] = f2bf(x[i]);
    } else if (i < NX + NW) {
      long j = i - NX;                 // j = n*512 + k  (WiT[n][k] = Wi[k][n])
      long n = j >> 9, k = j & 511;
      WiT[j] = f2bf(Wi[k * 1536 + n]);
    } else if (i < NX + 2 * NW) {
      long j = i - NX - NW;
      long n = j >> 9, k = j & 511;
      WhT[j] = f2bf(Wh[k * 1536 + n]);
    } else if (i < NX + 2 * NW + NH) {
      long j = i - NX - 2 * NW;
      Hb0[j] = f2bf(h0[j]);
    } else {
      bar[i - (NX + 2 * NW + NH)] = 0;
    }
  }
}

// ---------------- K2: Gi = Xb @ Wi + bi  (bf16 -> bf16) ----------------
__global__ void gi_gemm(const unsigned short* __restrict__ Xb,
                        const unsigned short* __restrict__ WiT,
                        const float* __restrict__ bi,
                        unsigned short* __restrict__ Gi) {
  __shared__ unsigned short As[128 * 32];
  __shared__ unsigned short Bs[128 * 32];
  const int tid  = threadIdx.x;
  const int m0   = blockIdx.x * 128;
  const int n0   = blockIdx.y * 128;
  const int lane = tid & 63, wv = tid >> 6;
  const int quad = lane >> 4, l16 = lane & 15;
  const int wm = (wv & 1) * 64, wn = (wv >> 1) * 64;
  const int sr = tid >> 1, sc = (tid & 1) * 16;

  floatx4 acc[4][4] = {};

  for (int kb = 0; kb < 16; ++kb) {
    const int k0 = kb * 32;
    __syncthreads();
    *(bhalf8*)(&As[sr * 32 + sc])     = *(const bhalf8*)(&Xb[(long)(m0 + sr) * 512 + k0 + sc]);
    *(bhalf8*)(&As[sr * 32 + sc + 8]) = *(const bhalf8*)(&Xb[(long)(m0 + sr) * 512 + k0 + sc + 8]);
    *(bhalf8*)(&Bs[sr * 32 + sc])     = *(const bhalf8*)(&WiT[(long)(n0 + sr) * 512 + k0 + sc]);
    *(bhalf8*)(&Bs[sr * 32 + sc + 8]) = *(const bhalf8*)(&WiT[(long)(n0 + sr) * 512 + k0 + sc + 8]);
    __syncthreads();

    bhalf8 af[4], bf[4];
#pragma unroll
    for (int i = 0; i < 4; ++i)
      af[i] = *(const bhalf8*)(&As[(wm + i * 16 + l16) * 32 + quad * 8]);
#pragma unroll
    for (int j = 0; j < 4; ++j)
      bf[j] = *(const bhalf8*)(&Bs[(wn + j * 16 + l16) * 32 + quad * 8]);
#pragma unroll
    for (int i = 0; i < 4; ++i)
#pragma unroll
      for (int j = 0; j < 4; ++j)
        acc[i][j] = __builtin_amdgcn_mfma_f32_16x16x32_bf16(af[i], bf[j], acc[i][j], 0, 0, 0);
  }

#pragma unroll
  for (int i = 0; i < 4; ++i)
#pragma unroll
    for (int j = 0; j < 4; ++j) {
      const int col = n0 + wn + j * 16 + l16;
      const float bv = bi[col];
#pragma unroll
      for (int r = 0; r < 4; ++r) {
        const int row = m0 + wm + i * 16 + quad * 4 + r;
        Gi[(long)row * 1536 + col] = f2bf(acc[i][j][r] + bv);
      }
    }
}

// ---------------- K3: persistent recurrence ----------------
__launch_bounds__(256, 1)
__global__ void recurrent_kernel(char* __restrict__ ws,
                                 const float* __restrict__ h0,
                                 const float* __restrict__ bhn,
                                 float* __restrict__ out) {
  const unsigned short* WhT = (const unsigned short*)(ws + O_WHT);
  const unsigned short* Gi  = (const unsigned short*)(ws + O_GI);
  int* bar     = (int*)(ws + O_BAR);
  int* cnt     = bar;            // [512] per-step fast counters
  int* flags   = bar + 512;      // [32]  agent-mode monotonic flags
  int* tick    = bar + 544;      // [8]   per-XCD claims
  int* arrived = bar + 552;
  int* tick2   = bar + 553;
  int* pcnt    = bar + 554;
  int* abortf  = bar + 555;
  int* arrive2 = bar + 556;

  const int tid = threadIdx.x;
  __shared__ int sdec[4];        // [0]=fastCandidate, [1]=slice, [2]=mode

  // ---- one-time election: try to gather 32 WGs on one XCD ----
  if (tid == 0) {
    const int xcc = (int)(__builtin_amdgcn_s_getreg((3 << 11) | 20)) & 7;  // HW_REG_XCC_ID
    const int slot = __hip_atomic_fetch_add(&tick[xcc], 1, __ATOMIC_SEQ_CST, __HIP_MEMORY_SCOPE_AGENT);
    __hip_atomic_fetch_add(arrived, 1, __ATOMIC_SEQ_CST, __HIP_MEMORY_SCOPE_AGENT);
    while (__hip_atomic_load(arrived, __ATOMIC_ACQUIRE, __HIP_MEMORY_SCOPE_AGENT) < NB_LAUNCH)
      __builtin_amdgcn_s_sleep(4);
    int best = -1, bxcd = 0;
    for (int c = 0; c < 8; ++c) {
      const int v = __hip_atomic_load(&tick[c], __ATOMIC_ACQUIRE, __HIP_MEMORY_SCOPE_AGENT);
      if (v > best) { best = v; bxcd = c; }
    }
    const int fastc = (best >= NWORK) ? 1 : 0;
    int slice = -1;
    if (fastc) {
      if (xcc == bxcd && slot < NWORK) slice = slot;
    } else {
      const int s2 = __hip_atomic_fetch_add(tick2, 1, __ATOMIC_SEQ_CST, __HIP_MEMORY_SCOPE_AGENT);
      if (s2 < NWORK) slice = s2;
    }
    sdec[0] = fastc; sdec[1] = slice;
  }
  __syncthreads();
  const int fastc = sdec[0];
  const int g     = sdec[1];     // hidden slice: units [16g, 16g+16)
  if (g < 0) return;

  // ---- probe: empirically verify same-L2 coherence among the 32 workers ----
  if (tid == 0) {
    int mode = 0;
    if (fastc) {
      __hip_atomic_fetch_add(pcnt, 1, __ATOMIC_RELAXED, __HIP_MEMORY_SCOPE_WORKGROUP);
      int ok = 0;
      for (int it = 0; it < 200000; ++it) {     // ~60M cyc cap; expected ~1k cyc
        int exp = NWORK;
        if (__hip_atomic_compare_exchange_strong(pcnt, &exp, NWORK,
                __ATOMIC_RELAXED, __ATOMIC_RELAXED, __HIP_MEMORY_SCOPE_WORKGROUP)) { ok = 1; break; }
      }
      if (!ok) __hip_atomic_fetch_add(abortf, 1, __ATOMIC_RELAXED, __HIP_MEMORY_SCOPE_AGENT);
      // agent-scope rendezvous (always terminates), then agree on mode
      __hip_atomic_fetch_add(arrive2, 1, __ATOMIC_ACQ_REL, __HIP_MEMORY_SCOPE_AGENT);
      while (__hip_atomic_load(arrive2, __ATOMIC_ACQUIRE, __HIP_MEMORY_SCOPE_AGENT) < NWORK)
        __builtin_amdgcn_s_sleep(2);
      mode = (__hip_atomic_load(abortf, __ATOMIC_ACQUIRE, __HIP_MEMORY_SCOPE_AGENT) > 0) ? 0 : 1;
    }
    sdec[2] = mode;
  }
  __syncthreads();
  const int fast = sdec[2];

  const int wv   = tid >> 6;          // M-tile (16 batch rows)
  const int lane = tid & 63;
  const int quad = lane >> 4, l16 = lane & 15;
  const int gcol = g * 16 + l16;      // this lane's hidden unit (C-layout col)

  // Wh fragments -> registers, persistent for all 512 steps.
  bhalf8 Bf[3][16];
#pragma unroll
  for (int gt = 0; gt < 3; ++gt) {
    const unsigned short* wp = WhT + (long)(gt * 512 + gcol) * 512;
#pragma unroll
    for (int ks = 0; ks < 16; ++ks)
      Bf[gt][ks] = *(const bhalf8*)(wp + ks * 32 + quad * 8);
  }
  const float bhn_v = bhn[gcol];

  float hprev[4];
#pragma unroll
  for (int r = 0; r < 4; ++r)
    hprev[r] = h0[(wv * 16 + quad * 4 + r) * 512 + gcol];

  // Gi prefetch for step 0
  float gi_r[4], gi_z[4], gi_n[4];
#pragma unroll
  for (int r = 0; r < 4; ++r) {
    const int brow = wv * 16 + quad * 4 + r;
    const long gb = (long)brow * 1536 + gcol;
    gi_r[r] = bf2f(Gi[gb]);
    gi_z[r] = bf2f(Gi[gb + 512]);
    gi_n[r] = bf2f(Gi[gb + 1024]);
  }

  for (int t = 0; t < T_STEPS; ++t) {
    const unsigned short* hin  = HS(ws, t);       // fresh address every step -> L1-cold
    unsigned short*       hout = HS(ws, t + 1);
    const unsigned short* ap = hin + (wv * 16 + l16) * 512 + quad * 8;

    // ---- load h A-frags ----
    bhalf8 af[16];
    if (fast) {
#pragma unroll
      for (int ks = 0; ks < 16; ++ks)
        af[ks] = *(const bhalf8*)(ap + ks * 32);   // L1 miss -> shared XCD L2 (fresh)
    } else {
#pragma unroll
      for (int ks = 0; ks < 16; ++ks) {
        union { unsigned long long q[2]; bhalf8 v; } u;
        u.q[0] = __hip_atomic_load((const unsigned long long*)(ap + ks * 32),
                                   __ATOMIC_RELAXED, __HIP_MEMORY_SCOPE_AGENT);
        u.q[1] = __hip_atomic_load((const unsigned long long*)(ap + ks * 32) + 1,
                                   __ATOMIC_RELAXED, __HIP_MEMORY_SCOPE_AGENT);
        af[ks] = u.v;
      }
    }

    floatx4 racc = {0.f, 0.f, 0.f, 0.f};
    floatx4 zacc = {0.f, 0.f, 0.f, 0.f};
    floatx4 nacc = {0.f, 0.f, 0.f, 0.f};
#pragma unroll
    for (int ks = 0; ks < 16; ++ks) {
      racc = __builtin_amdgcn_mfma_f32_16x16x32_bf16(af[ks], Bf[0][ks], racc, 0, 0, 0);
      zacc = __builtin_amdgcn_mfma_f32_16x16x32_bf16(af[ks], Bf[1][ks], zacc, 0, 0, 0);
      nacc = __builtin_amdgcn_mfma_f32_16x16x32_bf16(af[ks], Bf[2][ks], nacc, 0, 0, 0);
    }

    // ---- gates + h write (packed 2xbf16) ----
#pragma unroll
    for (int r = 0; r < 4; ++r) {
      const int brow = wv * 16 + quad * 4 + r;
      const float rg = 1.f / (1.f + __expf(-(gi_r[r] + racc[r])));
      const float zg = 1.f / (1.f + __expf(-(gi_z[r] + zacc[r])));
      const float pre = gi_n[r] + rg * (nacc[r] + bhn_v);
      const float e2 = __expf(2.f * pre);
      const float ng = 1.f - 2.f / (e2 + 1.f);      // tanh
      const float hn = (1.f - zg) * ng + zg * hprev[r];
      hprev[r] = hn;
      out[((long)t * 64 + brow) * 512 + gcol] = hn;
      const unsigned hb = (unsigned)f2bf(hn);
      const unsigned ob = __shfl_xor(hb, 1, 64);    // partner col (l16^1)
      if (!(l16 & 1)) {
        unsigned* dst = (unsigned*)(hout + brow * 512 + gcol);
        const unsigned packed = hb | (ob << 16);
        if (fast) *dst = packed;                    // write-through -> shared L2
        else __hip_atomic_store(dst, packed, __ATOMIC_RELAXED, __HIP_MEMORY_SCOPE_AGENT);
      }
    }

    // ---- prefetch next step's Gi (immutable; overlaps barrier) ----
    if (t + 1 < T_STEPS) {
      const long gibase = (long)(t + 1) * 64 * 1536;
#pragma unroll
      for (int r = 0; r < 4; ++r) {
        const int brow = wv * 16 + quad * 4 + r;
        const long gb = gibase + (long)brow * 1536 + gcol;
        gi_r[r] = bf2f(Gi[gb]);
        gi_z[r] = bf2f(Gi[gb + 512]);
        gi_n[r] = bf2f(Gi[gb + 1024]);
      }
    }

    // ---- per-step barrier ----
    const int want = t + 1;
    if (fast) {
      __syncthreads();                 // vmcnt(0): write-through h stores acked by L2
      if (tid == 0) {
        int* cw = &cnt[t];
        __hip_atomic_fetch_add(cw, 1, __ATOMIC_RELAXED, __HIP_MEMORY_SCOPE_WORKGROUP);
        int exp;
        do { exp = NWORK; } while (!__hip_atomic_compare_exchange_strong(cw, &exp, NWORK,
                 __ATOMIC_RELAXED, __ATOMIC_RELAXED, __HIP_MEMORY_SCOPE_WORKGROUP));
      }
      __syncthreads();
    } else {
      __syncthreads();
      if (tid == 0)
        __hip_atomic_store(&flags[g], want, __ATOMIC_RELAXED, __HIP_MEMORY_SCOPE_AGENT);
      int v;
      do {
        v = __hip_atomic_load(&flags[lane & 31], __ATOMIC_RELAXED, __HIP_MEMORY_SCOPE_AGENT);
      } while (!__all(v >= want));
      __atomic_signal_fence(__ATOMIC_SEQ_CST);
    }
  }
}

extern "C" void kernel_launch(void* const* d_in, const int* in_sizes, int n_in,
                              void* d_out, int out_size, void* d_ws, size_t ws_size,
                              hipStream_t stream) {
  const float* x   = (const float*)d_in[0];
  const float* h0  = (const float*)d_in[1];
  const float* Wi  = (const float*)d_in[2];
  const float* Wh  = (const float*)d_in[3];
  const float* bi  = (const float*)d_in[4];
  const float* bhn = (const float*)d_in[5];
  float* out = (float*)d_out;
  char* ws = (char*)d_ws;
  if (ws_size < WS_NEED) return;

  prep_kernel<<<4096, 256, 0, stream>>>(x, h0, Wi, Wh, ws);
  gi_gemm<<<dim3(256, 12), 256, 0, stream>>>(
      (const unsigned short*)(ws + O_XB), (const unsigned short*)(ws + O_WIT),
      bi, (unsigned short*)(ws + O_GI));
  recurrent_kernel<<<NB_LAUNCH, 256, 0, stream>>>(ws, h0, bhn, out);
}